// Round 1
// baseline (2140.317 us; speedup 1.0000x reference)
//
#include <hip/hip_runtime.h>

// MHA forward: out = (softmax(mask(QWq·(KWk)^T/8))·VWv)Wo + bo, plus attn probs.
// B=2, S=2048, H=16, Dk=64, D=1024. All fp32 this round (correctness baseline).
// d_out = [out (2*2048*1024)] ++ [attn (2*16*2048*2048)]
// d_ws  = Qp, Kp, Vp (each (B,H,S,64)) + ctx (B,S,1024)  -> 64 MB

#define D_MODEL 1024
#define NH      16
#define DK      64
#define BATCH   2
#define SEQ     2048
#define MTOT    (BATCH * SEQ)   // 4096

// ---------------------------------------------------------------------------
// GEMM: C = A(MxK) @ W(KxN) + bias. fp32, 128x128 tile, BK=8, 8x8 per thread.
// mode 0: C row-major (M x N).  mode 1: C in split-head (B, NH, SEQ, DK).
// ---------------------------------------------------------------------------
__global__ __launch_bounds__(256)
void gemm_bias_f32(const float* __restrict__ A, const float* __restrict__ W,
                   const float* __restrict__ bias, float* __restrict__ C,
                   int mode)
{
    const int K = D_MODEL, N = D_MODEL;
    __shared__ float As[8][128];   // As[k][m]
    __shared__ float Bs[8][128];   // Bs[k][n]
    const int tid = threadIdx.x;
    const int m0 = blockIdx.x * 128;
    const int n0 = blockIdx.y * 128;
    const int tx = tid & 15, ty = tid >> 4;

    float acc[8][8];
#pragma unroll
    for (int i = 0; i < 8; ++i)
#pragma unroll
        for (int j = 0; j < 8; ++j) acc[i][j] = 0.f;

    const int am = tid >> 1, ak = (tid & 1) * 4;
    const int bk = tid >> 5, bn = (tid & 31) * 4;
    const float* Ap = A + (size_t)(m0 + am) * K + ak;
    const float* Wp = W + (size_t)bk * N + n0 + bn;

    for (int k0 = 0; k0 < K; k0 += 8) {
        float4 av = *(const float4*)(Ap + k0);
        float4 wv = *(const float4*)(Wp + (size_t)k0 * N);
        __syncthreads();
        As[ak + 0][am] = av.x;
        As[ak + 1][am] = av.y;
        As[ak + 2][am] = av.z;
        As[ak + 3][am] = av.w;
        *(float4*)&Bs[bk][bn] = wv;
        __syncthreads();
#pragma unroll
        for (int kk = 0; kk < 8; ++kk) {
            float a[8], b[8];
            *(float4*)&a[0] = *(const float4*)&As[kk][ty * 8];
            *(float4*)&a[4] = *(const float4*)&As[kk][ty * 8 + 4];
            *(float4*)&b[0] = *(const float4*)&Bs[kk][tx * 8];
            *(float4*)&b[4] = *(const float4*)&Bs[kk][tx * 8 + 4];
#pragma unroll
            for (int i = 0; i < 8; ++i)
#pragma unroll
                for (int j = 0; j < 8; ++j)
                    acc[i][j] = fmaf(a[i], b[j], acc[i][j]);
        }
    }

    float bvals[8];
#pragma unroll
    for (int j = 0; j < 8; ++j) bvals[j] = bias[n0 + tx * 8 + j];

#pragma unroll
    for (int i = 0; i < 8; ++i) {
        const int m = m0 + ty * 8 + i;
        float4 r0, r1;
        r0.x = acc[i][0] + bvals[0]; r0.y = acc[i][1] + bvals[1];
        r0.z = acc[i][2] + bvals[2]; r0.w = acc[i][3] + bvals[3];
        r1.x = acc[i][4] + bvals[4]; r1.y = acc[i][5] + bvals[5];
        r1.z = acc[i][6] + bvals[6]; r1.w = acc[i][7] + bvals[7];
        if (mode == 0) {
            float* dst = C + (size_t)m * N + n0 + tx * 8;
            *(float4*)dst = r0;
            *(float4*)(dst + 4) = r1;
        } else {
            const int b = m >> 11, s = m & (SEQ - 1);
            const int n = n0 + tx * 8;
            const int h = n >> 6, d = n & 63;   // tx*8..+7 never crosses a head
            float* dst = C + (((size_t)b * NH + h) * SEQ + s) * DK + d;
            *(float4*)dst = r0;
            *(float4*)(dst + 4) = r1;
        }
    }
}

// ---------------------------------------------------------------------------
// Fused causal attention, two-pass online softmax per 64-row q-tile.
// grid = (SEQ/64, BATCH*NH), block = 256 (16x16 threads, 4x4 micro-tiles).
// Writes normalized attn (incl. zeros in masked region) and ctx (B,S,D).
// ---------------------------------------------------------------------------
__global__ __launch_bounds__(256)
void attn_fused(const float* __restrict__ Qp, const float* __restrict__ Kp,
                const float* __restrict__ Vp, float* __restrict__ attn,
                float* __restrict__ ctx)
{
    __shared__ float Qs[64][64];    // Q^T: [d][r]
    __shared__ float KVs[64][64];   // K^T: [d][c] during scores; V: [c][d] during PV
    __shared__ union {
        float Ps[64][72];           // P: [r][c], padded row (72 floats, 16B-aligned)
        struct { float m[64][16]; float l[64][16]; } red;
    } u;
    __shared__ float m_row[64];
    __shared__ float linv_row[64];

    const int tid = threadIdx.x;
    const int qt = blockIdx.x;           // q tile 0..31
    const int bh = blockIdx.y;           // 0..31
    const int q0 = qt * 64;
    const float* Qh = Qp + (size_t)bh * SEQ * DK;
    const float* Kh = Kp + (size_t)bh * SEQ * DK;
    const float* Vh = Vp + (size_t)bh * SEQ * DK;
    float* attn_h = attn + (size_t)bh * SEQ * SEQ;
    const int bb = bh >> 4, hh = bh & 15;
    float* ctx_h = ctx + (size_t)bb * SEQ * D_MODEL + hh * DK;

    const int tx = tid & 15, ty = tid >> 4;
    const int sr = tid >> 2;             // staging row 0..63
    const int sd = (tid & 3) * 16;       // staging d base

    // stage Q^T once
    {
        const float* src = Qh + (size_t)(q0 + sr) * DK + sd;
#pragma unroll
        for (int k = 0; k < 4; ++k) {
            float4 v = *(const float4*)(src + 4 * k);
            Qs[sd + 4 * k + 0][sr] = v.x;
            Qs[sd + 4 * k + 1][sr] = v.y;
            Qs[sd + 4 * k + 2][sr] = v.z;
            Qs[sd + 4 * k + 3][sr] = v.w;
        }
    }

    float run_m[4], run_l[4];
#pragma unroll
    for (int i = 0; i < 4; ++i) { run_m[i] = -1e30f; run_l[i] = 0.f; }

    // ---------------- pass 1: row max + sumexp ----------------
    for (int kt = 0; kt <= qt; ++kt) {
        __syncthreads();
        {   // stage K^T
            const float* src = Kh + (size_t)(kt * 64 + sr) * DK + sd;
#pragma unroll
            for (int k = 0; k < 4; ++k) {
                float4 v = *(const float4*)(src + 4 * k);
                KVs[sd + 4 * k + 0][sr] = v.x;
                KVs[sd + 4 * k + 1][sr] = v.y;
                KVs[sd + 4 * k + 2][sr] = v.z;
                KVs[sd + 4 * k + 3][sr] = v.w;
            }
        }
        __syncthreads();
        float s[4][4];
#pragma unroll
        for (int i = 0; i < 4; ++i)
#pragma unroll
            for (int j = 0; j < 4; ++j) s[i][j] = 0.f;
#pragma unroll 8
        for (int d = 0; d < 64; ++d) {
            float4 qa = *(const float4*)&Qs[d][ty * 4];
            float4 kb = *(const float4*)&KVs[d][tx * 4];
            float a[4] = {qa.x, qa.y, qa.z, qa.w};
            float b[4] = {kb.x, kb.y, kb.z, kb.w};
#pragma unroll
            for (int i = 0; i < 4; ++i)
#pragma unroll
                for (int j = 0; j < 4; ++j)
                    s[i][j] = fmaf(a[i], b[j], s[i][j]);
        }
#pragma unroll
        for (int i = 0; i < 4; ++i) {
            const int rg = q0 + ty * 4 + i;
            float sv[4]; float tm = -1e30f;
#pragma unroll
            for (int j = 0; j < 4; ++j) {
                const int cg = kt * 64 + tx * 4 + j;
                float x = s[i][j] * 0.125f;
                if (cg > rg) x = -1e30f;
                sv[j] = x;
                tm = fmaxf(tm, x);
            }
            // online merge; all-masked threads keep m=-1e30 and garbage l,
            // which is annihilated by exp(-1e30 - m_row)=0 at merge time.
            const float nm = fmaxf(run_m[i], tm);
            float l = run_l[i] * __expf(run_m[i] - nm);
#pragma unroll
            for (int j = 0; j < 4; ++j) l += __expf(sv[j] - nm);
            run_m[i] = nm; run_l[i] = l;
        }
    }

    // reduce (m,l) across the 16 tx threads sharing each row
    __syncthreads();
#pragma unroll
    for (int i = 0; i < 4; ++i) {
        u.red.m[ty * 4 + i][tx] = run_m[i];
        u.red.l[ty * 4 + i][tx] = run_l[i];
    }
    __syncthreads();
    if (tid < 64) {
        float m = -1e30f;
#pragma unroll
        for (int t = 0; t < 16; ++t) m = fmaxf(m, u.red.m[tid][t]);
        float l = 0.f;
#pragma unroll
        for (int t = 0; t < 16; ++t)
            l += u.red.l[tid][t] * __expf(u.red.m[tid][t] - m);
        m_row[tid] = m;
        linv_row[tid] = 1.f / l;
    }

    // ---------------- pass 2: write attn, accumulate ctx ----------------
    float facc[4][4];
#pragma unroll
    for (int i = 0; i < 4; ++i)
#pragma unroll
        for (int j = 0; j < 4; ++j) facc[i][j] = 0.f;

    for (int kt = 0; kt < SEQ / 64; ++kt) {
        __syncthreads();
        if (kt <= qt) {
            {   // stage K^T
                const float* src = Kh + (size_t)(kt * 64 + sr) * DK + sd;
#pragma unroll
                for (int k = 0; k < 4; ++k) {
                    float4 v = *(const float4*)(src + 4 * k);
                    KVs[sd + 4 * k + 0][sr] = v.x;
                    KVs[sd + 4 * k + 1][sr] = v.y;
                    KVs[sd + 4 * k + 2][sr] = v.z;
                    KVs[sd + 4 * k + 3][sr] = v.w;
                }
            }
            __syncthreads();
            float s[4][4];
#pragma unroll
            for (int i = 0; i < 4; ++i)
#pragma unroll
                for (int j = 0; j < 4; ++j) s[i][j] = 0.f;
#pragma unroll 8
            for (int d = 0; d < 64; ++d) {
                float4 qa = *(const float4*)&Qs[d][ty * 4];
                float4 kb = *(const float4*)&KVs[d][tx * 4];
                float a[4] = {qa.x, qa.y, qa.z, qa.w};
                float b[4] = {kb.x, kb.y, kb.z, kb.w};
#pragma unroll
                for (int i = 0; i < 4; ++i)
#pragma unroll
                    for (int j = 0; j < 4; ++j)
                        s[i][j] = fmaf(a[i], b[j], s[i][j]);
            }
            float p[4][4];
#pragma unroll
            for (int i = 0; i < 4; ++i) {
                const int rg = q0 + ty * 4 + i;
                const float m = m_row[ty * 4 + i];
                const float linv = linv_row[ty * 4 + i];
#pragma unroll
                for (int j = 0; j < 4; ++j) {
                    const int cg = kt * 64 + tx * 4 + j;
                    const float x = s[i][j] * 0.125f;
                    p[i][j] = (cg <= rg) ? __expf(x - m) * linv : 0.f;
                }
            }
            // write attn + stage P
#pragma unroll
            for (int i = 0; i < 4; ++i) {
                float4 pv;
                pv.x = p[i][0]; pv.y = p[i][1]; pv.z = p[i][2]; pv.w = p[i][3];
                *(float4*)&attn_h[(size_t)(q0 + ty * 4 + i) * SEQ + kt * 64 + tx * 4] = pv;
                *(float4*)&u.Ps[ty * 4 + i][tx * 4] = pv;
            }
            __syncthreads();   // P visible; scores done reading KVs
            {   // stage V (overwrites K^T)
                const float* src = Vh + (size_t)(kt * 64 + sr) * DK + sd;
#pragma unroll
                for (int k = 0; k < 4; ++k)
                    *(float4*)&KVs[sr][sd + 4 * k] = *(const float4*)(src + 4 * k);
            }
            __syncthreads();
            // ctx[r][d] += P[r][c] * V[c][d]
#pragma unroll 4
            for (int c0 = 0; c0 < 64; c0 += 4) {
                float4 pr[4], vr[4];
#pragma unroll
                for (int i = 0; i < 4; ++i) pr[i] = *(const float4*)&u.Ps[ty * 4 + i][c0];
#pragma unroll
                for (int cc = 0; cc < 4; ++cc) vr[cc] = *(const float4*)&KVs[c0 + cc][tx * 4];
#pragma unroll
                for (int i = 0; i < 4; ++i) {
                    const float pi[4] = {pr[i].x, pr[i].y, pr[i].z, pr[i].w};
#pragma unroll
                    for (int cc = 0; cc < 4; ++cc) {
                        facc[i][0] = fmaf(pi[cc], vr[cc].x, facc[i][0]);
                        facc[i][1] = fmaf(pi[cc], vr[cc].y, facc[i][1]);
                        facc[i][2] = fmaf(pi[cc], vr[cc].z, facc[i][2]);
                        facc[i][3] = fmaf(pi[cc], vr[cc].w, facc[i][3]);
                    }
                }
            }
        } else {
            // masked tile: d_out is poisoned, must write zeros
            const float4 z = make_float4(0.f, 0.f, 0.f, 0.f);
#pragma unroll
            for (int i = 0; i < 4; ++i)
                *(float4*)&attn_h[(size_t)(q0 + ty * 4 + i) * SEQ + kt * 64 + tx * 4] = z;
        }
    }

    // write ctx in (B,S,D) layout
#pragma unroll
    for (int i = 0; i < 4; ++i) {
        float4 r;
        r.x = facc[i][0]; r.y = facc[i][1]; r.z = facc[i][2]; r.w = facc[i][3];
        *(float4*)&ctx_h[(size_t)(q0 + ty * 4 + i) * D_MODEL + tx * 4] = r;
    }
}

// ---------------------------------------------------------------------------
extern "C" void kernel_launch(void* const* d_in, const int* in_sizes, int n_in,
                              void* d_out, int out_size, void* d_ws, size_t ws_size,
                              hipStream_t stream)
{
    const float* q  = (const float*)d_in[0];
    const float* k  = (const float*)d_in[1];
    const float* v  = (const float*)d_in[2];
    // d_in[3] = mask: causal tril by construction; we use col<=row directly.
    const float* wq = (const float*)d_in[4];
    const float* bq = (const float*)d_in[5];
    const float* wk = (const float*)d_in[6];
    const float* bk = (const float*)d_in[7];
    const float* wv = (const float*)d_in[8];
    const float* bv = (const float*)d_in[9];
    const float* wo = (const float*)d_in[10];
    const float* bo = (const float*)d_in[11];

    float* out  = (float*)d_out;
    float* attn = out + (size_t)BATCH * SEQ * D_MODEL;

    float* Qp  = (float*)d_ws;                       // (B,H,S,64)
    float* Kp  = Qp + (size_t)MTOT * D_MODEL;
    float* Vp  = Kp + (size_t)MTOT * D_MODEL;
    float* ctx = Vp + (size_t)MTOT * D_MODEL;        // (B,S,D)

    dim3 gg(MTOT / 128, D_MODEL / 128);              // 32 x 8
    gemm_bias_f32<<<gg, 256, 0, stream>>>(q, wq, bq, Qp, 1);
    gemm_bias_f32<<<gg, 256, 0, stream>>>(k, wk, bk, Kp, 1);
    gemm_bias_f32<<<gg, 256, 0, stream>>>(v, wv, bv, Vp, 1);

    dim3 ga(SEQ / 64, BATCH * NH);                   // 32 x 32
    attn_fused<<<ga, 256, 0, stream>>>(Qp, Kp, Vp, attn, ctx);

    gemm_bias_f32<<<gg, 256, 0, stream>>>(ctx, wo, bo, out, 0);
}

// Round 2
// 1368.079 us; speedup vs baseline: 1.5645x; 1.5645x over previous
//
#include <hip/hip_runtime.h>

// MHA forward, round 2: bf16 MFMA projections (m97 structure), attn unchanged
// logic but bf16 Q/K/V in, bf16 ctx out.
// d_out = [out fp32 (2*2048*1024)] ++ [attn fp32 (2*16*2048*2048)]
// d_ws (ushort units): qb,kb,vb | wqT,wkT,wvT,woT | Qp,Kp,Vp | ctxb  = 67.1 MB

#define D_MODEL 1024
#define NH      16
#define DK      64
#define BATCH   2
#define SEQ     2048
#define MTOT    (BATCH * SEQ)   // 4096

typedef __attribute__((ext_vector_type(8))) short bf16x8;
typedef __attribute__((ext_vector_type(4))) float f32x4;

__device__ __forceinline__ unsigned short f2bf(float f) {
    unsigned u = __float_as_uint(f);
    u += 0x7fff + ((u >> 16) & 1);          // RTN-even
    return (unsigned short)(u >> 16);
}
__device__ __forceinline__ float bflo(unsigned u) { return __uint_as_float(u << 16); }
__device__ __forceinline__ float bfhi(unsigned u) { return __uint_as_float(u & 0xffff0000u); }

__device__ __forceinline__ void async_ld16(void* lds, const void* g) {
    __builtin_amdgcn_global_load_lds(
        (const __attribute__((address_space(1))) void*)g,
        (__attribute__((address_space(3))) void*)lds, 16, 0, 0);
}

// ---------------------------------------------------------------------------
// cast fp32 -> bf16, 4 elems/thread
// ---------------------------------------------------------------------------
__global__ __launch_bounds__(256)
void cast_f32_bf16(const float* __restrict__ src, unsigned short* __restrict__ dst, int n4)
{
    int i = blockIdx.x * 256 + threadIdx.x;
    if (i < n4) {
        float4 v = ((const float4*)src)[i];
        uint2 w;
        w.x = (unsigned)f2bf(v.x) | ((unsigned)f2bf(v.y) << 16);
        w.y = (unsigned)f2bf(v.z) | ((unsigned)f2bf(v.w) << 16);
        ((uint2*)dst)[i] = w;
    }
}

// ---------------------------------------------------------------------------
// transpose+cast weights: W[K][N] fp32 -> Wt[N][K] bf16. grid (32,32,4), 256 thr.
// ---------------------------------------------------------------------------
__global__ __launch_bounds__(256)
void transpose_cast_w(const float* __restrict__ w0, const float* __restrict__ w1,
                      const float* __restrict__ w2, const float* __restrict__ w3,
                      unsigned short* __restrict__ dst)
{
    const float* W = blockIdx.z == 0 ? w0 : blockIdx.z == 1 ? w1 : blockIdx.z == 2 ? w2 : w3;
    unsigned short* Wt = dst + (size_t)blockIdx.z * (D_MODEL * D_MODEL);
    __shared__ float t[32][33];
    const int tx = threadIdx.x & 31, ty = threadIdx.x >> 5;   // 32 x 8
    const int k0 = blockIdx.x * 32, n0 = blockIdx.y * 32;
#pragma unroll
    for (int r = 0; r < 4; ++r)
        t[ty + r * 8][tx] = W[(size_t)(k0 + ty + r * 8) * D_MODEL + n0 + tx];
    __syncthreads();
#pragma unroll
    for (int r = 0; r < 4; ++r)
        Wt[(size_t)(n0 + ty + r * 8) * D_MODEL + k0 + tx] = f2bf(t[tx][ty + r * 8]);
}

// ---------------------------------------------------------------------------
// bf16 MFMA GEMM: C = A(4096xK) @ Wt^T + bias.  K = N = 1024.
// A row-major bf16, Wt is [N][K] bf16. Tile 128x128, BK=32, 4 waves, m97 style.
// mode 0: dst bf16 split-head (B,NH,SEQ,DK), z selects {A0,A1,A2}/{Wt slab}/{b,D}.
// mode 1: dst fp32 row-major (Dout).
// ---------------------------------------------------------------------------
__global__ __launch_bounds__(256)
void gemm_mfma(const unsigned short* __restrict__ A0, const unsigned short* __restrict__ A1,
               const unsigned short* __restrict__ A2, const unsigned short* __restrict__ WT,
               const float* __restrict__ b0, const float* __restrict__ b1,
               const float* __restrict__ b2,
               unsigned short* __restrict__ D0, unsigned short* __restrict__ D1,
               unsigned short* __restrict__ D2, float* __restrict__ Dout, int mode)
{
    const int K = D_MODEL;
    __shared__ unsigned short As[128 * 32];   // [m][k]
    __shared__ unsigned short Bs[128 * 32];   // [n][k]

    const int z = blockIdx.z;
    const unsigned short* A = (mode == 0) ? (z == 0 ? A0 : z == 1 ? A1 : A2) : A0;
    const unsigned short* Wt = (mode == 0) ? WT + (size_t)z * (D_MODEL * D_MODEL) : WT;
    const float* bias = (z == 0 ? b0 : z == 1 ? b1 : b2);

    const int tid = threadIdx.x;
    const int wave = tid >> 6, lane = tid & 63;
    const int quad = lane >> 4, l15 = lane & 15;
    const int m0 = blockIdx.x * 128, n0 = blockIdx.y * 128;
    const int wm = (wave & 1) * 64, wn = (wave >> 1) * 64;

    // staging addresses: each wave issues 2 A-loads + 2 B-loads of 1024B
    const int srow = (lane >> 2);              // 0..15 within a 16-row chunk
    const int skel = (lane & 3) * 8;           // k element 0/8/16/24
    const unsigned short* gA0 = A  + (size_t)(m0 + wave * 32 +      srow) * K + skel;
    const unsigned short* gA1 = A  + (size_t)(m0 + wave * 32 + 16 + srow) * K + skel;
    const unsigned short* gB0 = Wt + (size_t)(n0 + wave * 32 +      srow) * K + skel;
    const unsigned short* gB1 = Wt + (size_t)(n0 + wave * 32 + 16 + srow) * K + skel;
    unsigned short* lA0 = &As[(wave * 2 + 0) * 512];
    unsigned short* lA1 = &As[(wave * 2 + 1) * 512];
    unsigned short* lB0 = &Bs[(wave * 2 + 0) * 512];
    unsigned short* lB1 = &Bs[(wave * 2 + 1) * 512];

    f32x4 acc[4][4];
#pragma unroll
    for (int i = 0; i < 4; ++i)
#pragma unroll
        for (int j = 0; j < 4; ++j) acc[i][j] = (f32x4){0.f, 0.f, 0.f, 0.f};

    for (int k0 = 0; k0 < K; k0 += 32) {
        __syncthreads();
        async_ld16(lA0, gA0 + k0);
        async_ld16(lA1, gA1 + k0);
        async_ld16(lB0, gB0 + k0);
        async_ld16(lB1, gB1 + k0);
        __syncthreads();
        bf16x8 a[4], b[4];
#pragma unroll
        for (int i = 0; i < 4; ++i)
            a[i] = *(const bf16x8*)&As[(wm + i * 16 + l15) * 32 + quad * 8];
#pragma unroll
        for (int j = 0; j < 4; ++j)
            b[j] = *(const bf16x8*)&Bs[(wn + j * 16 + l15) * 32 + quad * 8];
#pragma unroll
        for (int i = 0; i < 4; ++i)
#pragma unroll
            for (int j = 0; j < 4; ++j)
                acc[i][j] = __builtin_amdgcn_mfma_f32_16x16x32_bf16(a[i], b[j], acc[i][j], 0, 0, 0);
    }

    // epilogue: D row = m0+wm+i*16+quad*4+r, col = n0+wn+j*16+l15
    unsigned short* Dh = (z == 0 ? D0 : z == 1 ? D1 : D2);
#pragma unroll
    for (int j = 0; j < 4; ++j) {
        const int col = n0 + wn + j * 16 + l15;
        const float bv = bias[col];
        const int h = col >> 6, d = col & 63;
#pragma unroll
        for (int i = 0; i < 4; ++i) {
            const int row0 = m0 + wm + i * 16 + quad * 4;
#pragma unroll
            for (int r = 0; r < 4; ++r) {
                const int row = row0 + r;
                const float val = acc[i][j][r] + bv;
                if (mode == 0) {
                    const int bb = row >> 11, ss = row & (SEQ - 1);
                    Dh[(((size_t)bb * NH + h) * SEQ + ss) * DK + d] = f2bf(val);
                } else {
                    Dout[(size_t)row * D_MODEL + col] = val;
                }
            }
        }
    }
}

// ---------------------------------------------------------------------------
// Fused causal attention (round-1 logic), bf16 inputs, bf16 ctx output.
// grid = (SEQ/64, BATCH*NH), block = 256 (16x16 threads, 4x4 micro-tiles).
// ---------------------------------------------------------------------------
__global__ __launch_bounds__(256)
void attn_fused(const unsigned short* __restrict__ Qp, const unsigned short* __restrict__ Kp,
                const unsigned short* __restrict__ Vp, float* __restrict__ attn,
                unsigned short* __restrict__ ctxb)
{
    __shared__ float Qs[64][64];    // Q^T: [d][r]
    __shared__ float KVs[64][64];   // K^T: [d][c] during scores; V: [c][d] during PV
    __shared__ union {
        float Ps[64][72];
        struct { float m[64][16]; float l[64][16]; } red;
    } u;
    __shared__ float m_row[64];
    __shared__ float linv_row[64];

    const int tid = threadIdx.x;
    const int qt = blockIdx.x;
    const int bh = blockIdx.y;
    const int q0 = qt * 64;
    const unsigned short* Qh = Qp + (size_t)bh * SEQ * DK;
    const unsigned short* Kh = Kp + (size_t)bh * SEQ * DK;
    const unsigned short* Vh = Vp + (size_t)bh * SEQ * DK;
    float* attn_h = attn + (size_t)bh * SEQ * SEQ;
    const int bb = bh >> 4, hh = bh & 15;
    unsigned short* ctx_h = ctxb + (size_t)bb * SEQ * D_MODEL + hh * DK;

    const int tx = tid & 15, ty = tid >> 4;
    const int sr = tid >> 2;             // staging row 0..63
    const int sd = (tid & 3) * 16;       // staging d base

    // stage Q^T once (bf16 -> fp32)
    {
        const unsigned short* src = Qh + (size_t)(q0 + sr) * DK + sd;
        uint4 ua = *(const uint4*)src;
        uint4 ub = *(const uint4*)(src + 8);
        Qs[sd +  0][sr] = bflo(ua.x); Qs[sd +  1][sr] = bfhi(ua.x);
        Qs[sd +  2][sr] = bflo(ua.y); Qs[sd +  3][sr] = bfhi(ua.y);
        Qs[sd +  4][sr] = bflo(ua.z); Qs[sd +  5][sr] = bfhi(ua.z);
        Qs[sd +  6][sr] = bflo(ua.w); Qs[sd +  7][sr] = bfhi(ua.w);
        Qs[sd +  8][sr] = bflo(ub.x); Qs[sd +  9][sr] = bfhi(ub.x);
        Qs[sd + 10][sr] = bflo(ub.y); Qs[sd + 11][sr] = bfhi(ub.y);
        Qs[sd + 12][sr] = bflo(ub.z); Qs[sd + 13][sr] = bfhi(ub.z);
        Qs[sd + 14][sr] = bflo(ub.w); Qs[sd + 15][sr] = bfhi(ub.w);
    }

    float run_m[4], run_l[4];
#pragma unroll
    for (int i = 0; i < 4; ++i) { run_m[i] = -1e30f; run_l[i] = 0.f; }

    // ---------------- pass 1: row max + sumexp ----------------
    for (int kt = 0; kt <= qt; ++kt) {
        __syncthreads();
        {   // stage K^T
            const unsigned short* src = Kh + (size_t)(kt * 64 + sr) * DK + sd;
            uint4 ua = *(const uint4*)src;
            uint4 ub = *(const uint4*)(src + 8);
            KVs[sd +  0][sr] = bflo(ua.x); KVs[sd +  1][sr] = bfhi(ua.x);
            KVs[sd +  2][sr] = bflo(ua.y); KVs[sd +  3][sr] = bfhi(ua.y);
            KVs[sd +  4][sr] = bflo(ua.z); KVs[sd +  5][sr] = bfhi(ua.z);
            KVs[sd +  6][sr] = bflo(ua.w); KVs[sd +  7][sr] = bfhi(ua.w);
            KVs[sd +  8][sr] = bflo(ub.x); KVs[sd +  9][sr] = bfhi(ub.x);
            KVs[sd + 10][sr] = bflo(ub.y); KVs[sd + 11][sr] = bfhi(ub.y);
            KVs[sd + 12][sr] = bflo(ub.z); KVs[sd + 13][sr] = bfhi(ub.z);
            KVs[sd + 14][sr] = bflo(ub.w); KVs[sd + 15][sr] = bfhi(ub.w);
        }
        __syncthreads();
        float s[4][4];
#pragma unroll
        for (int i = 0; i < 4; ++i)
#pragma unroll
            for (int j = 0; j < 4; ++j) s[i][j] = 0.f;
#pragma unroll 8
        for (int d = 0; d < 64; ++d) {
            float4 qa = *(const float4*)&Qs[d][ty * 4];
            float4 kb = *(const float4*)&KVs[d][tx * 4];
            float a[4] = {qa.x, qa.y, qa.z, qa.w};
            float b[4] = {kb.x, kb.y, kb.z, kb.w};
#pragma unroll
            for (int i = 0; i < 4; ++i)
#pragma unroll
                for (int j = 0; j < 4; ++j)
                    s[i][j] = fmaf(a[i], b[j], s[i][j]);
        }
#pragma unroll
        for (int i = 0; i < 4; ++i) {
            const int rg = q0 + ty * 4 + i;
            float sv[4]; float tm = -1e30f;
#pragma unroll
            for (int j = 0; j < 4; ++j) {
                const int cg = kt * 64 + tx * 4 + j;
                float x = s[i][j] * 0.125f;
                if (cg > rg) x = -1e30f;
                sv[j] = x;
                tm = fmaxf(tm, x);
            }
            const float nm = fmaxf(run_m[i], tm);
            float l = run_l[i] * __expf(run_m[i] - nm);
#pragma unroll
            for (int j = 0; j < 4; ++j) l += __expf(sv[j] - nm);
            run_m[i] = nm; run_l[i] = l;
        }
    }

    __syncthreads();
#pragma unroll
    for (int i = 0; i < 4; ++i) {
        u.red.m[ty * 4 + i][tx] = run_m[i];
        u.red.l[ty * 4 + i][tx] = run_l[i];
    }
    __syncthreads();
    if (tid < 64) {
        float m = -1e30f;
#pragma unroll
        for (int t = 0; t < 16; ++t) m = fmaxf(m, u.red.m[tid][t]);
        float l = 0.f;
#pragma unroll
        for (int t = 0; t < 16; ++t)
            l += u.red.l[tid][t] * __expf(u.red.m[tid][t] - m);
        m_row[tid] = m;
        linv_row[tid] = 1.f / l;
    }

    // ---------------- pass 2: write attn, accumulate ctx ----------------
    float facc[4][4];
#pragma unroll
    for (int i = 0; i < 4; ++i)
#pragma unroll
        for (int j = 0; j < 4; ++j) facc[i][j] = 0.f;

    for (int kt = 0; kt < SEQ / 64; ++kt) {
        __syncthreads();
        if (kt <= qt) {
            {   // stage K^T
                const unsigned short* src = Kh + (size_t)(kt * 64 + sr) * DK + sd;
                uint4 ua = *(const uint4*)src;
                uint4 ub = *(const uint4*)(src + 8);
                KVs[sd +  0][sr] = bflo(ua.x); KVs[sd +  1][sr] = bfhi(ua.x);
                KVs[sd +  2][sr] = bflo(ua.y); KVs[sd +  3][sr] = bfhi(ua.y);
                KVs[sd +  4][sr] = bflo(ua.z); KVs[sd +  5][sr] = bfhi(ua.z);
                KVs[sd +  6][sr] = bflo(ua.w); KVs[sd +  7][sr] = bfhi(ua.w);
                KVs[sd +  8][sr] = bflo(ub.x); KVs[sd +  9][sr] = bfhi(ub.x);
                KVs[sd + 10][sr] = bflo(ub.y); KVs[sd + 11][sr] = bfhi(ub.y);
                KVs[sd + 12][sr] = bflo(ub.z); KVs[sd + 13][sr] = bfhi(ub.z);
                KVs[sd + 14][sr] = bflo(ub.w); KVs[sd + 15][sr] = bfhi(ub.w);
            }
            __syncthreads();
            float s[4][4];
#pragma unroll
            for (int i = 0; i < 4; ++i)
#pragma unroll
                for (int j = 0; j < 4; ++j) s[i][j] = 0.f;
#pragma unroll 8
            for (int d = 0; d < 64; ++d) {
                float4 qa = *(const float4*)&Qs[d][ty * 4];
                float4 kb = *(const float4*)&KVs[d][tx * 4];
                float a[4] = {qa.x, qa.y, qa.z, qa.w};
                float b[4] = {kb.x, kb.y, kb.z, kb.w};
#pragma unroll
                for (int i = 0; i < 4; ++i)
#pragma unroll
                    for (int j = 0; j < 4; ++j)
                        s[i][j] = fmaf(a[i], b[j], s[i][j]);
            }
            float p[4][4];
#pragma unroll
            for (int i = 0; i < 4; ++i) {
                const int rg = q0 + ty * 4 + i;
                const float m = m_row[ty * 4 + i];
                const float linv = linv_row[ty * 4 + i];
#pragma unroll
                for (int j = 0; j < 4; ++j) {
                    const int cg = kt * 64 + tx * 4 + j;
                    const float x = s[i][j] * 0.125f;
                    p[i][j] = (cg <= rg) ? __expf(x - m) * linv : 0.f;
                }
            }
#pragma unroll
            for (int i = 0; i < 4; ++i) {
                float4 pv;
                pv.x = p[i][0]; pv.y = p[i][1]; pv.z = p[i][2]; pv.w = p[i][3];
                *(float4*)&attn_h[(size_t)(q0 + ty * 4 + i) * SEQ + kt * 64 + tx * 4] = pv;
                *(float4*)&u.Ps[ty * 4 + i][tx * 4] = pv;
            }
            __syncthreads();
            {   // stage V (row-major, overwrites K^T)
                const unsigned short* src = Vh + (size_t)(kt * 64 + sr) * DK + sd;
                uint4 ua = *(const uint4*)src;
                uint4 ub = *(const uint4*)(src + 8);
                *(float4*)&KVs[sr][sd +  0] = make_float4(bflo(ua.x), bfhi(ua.x), bflo(ua.y), bfhi(ua.y));
                *(float4*)&KVs[sr][sd +  4] = make_float4(bflo(ua.z), bfhi(ua.z), bflo(ua.w), bfhi(ua.w));
                *(float4*)&KVs[sr][sd +  8] = make_float4(bflo(ub.x), bfhi(ub.x), bflo(ub.y), bfhi(ub.y));
                *(float4*)&KVs[sr][sd + 12] = make_float4(bflo(ub.z), bfhi(ub.z), bflo(ub.w), bfhi(ub.w));
            }
            __syncthreads();
#pragma unroll 4
            for (int c0 = 0; c0 < 64; c0 += 4) {
                float4 pr[4], vr[4];
#pragma unroll
                for (int i = 0; i < 4; ++i) pr[i] = *(const float4*)&u.Ps[ty * 4 + i][c0];
#pragma unroll
                for (int cc = 0; cc < 4; ++cc) vr[cc] = *(const float4*)&KVs[c0 + cc][tx * 4];
#pragma unroll
                for (int i = 0; i < 4; ++i) {
                    const float pi[4] = {pr[i].x, pr[i].y, pr[i].z, pr[i].w};
#pragma unroll
                    for (int cc = 0; cc < 4; ++cc) {
                        facc[i][0] = fmaf(pi[cc], vr[cc].x, facc[i][0]);
                        facc[i][1] = fmaf(pi[cc], vr[cc].y, facc[i][1]);
                        facc[i][2] = fmaf(pi[cc], vr[cc].z, facc[i][2]);
                        facc[i][3] = fmaf(pi[cc], vr[cc].w, facc[i][3]);
                    }
                }
            }
        } else {
            const float4 z = make_float4(0.f, 0.f, 0.f, 0.f);
#pragma unroll
            for (int i = 0; i < 4; ++i)
                *(float4*)&attn_h[(size_t)(q0 + ty * 4 + i) * SEQ + kt * 64 + tx * 4] = z;
        }
    }

    // write ctx (bf16, B,S,D layout)
#pragma unroll
    for (int i = 0; i < 4; ++i) {
        uint2 w;
        w.x = (unsigned)f2bf(facc[i][0]) | ((unsigned)f2bf(facc[i][1]) << 16);
        w.y = (unsigned)f2bf(facc[i][2]) | ((unsigned)f2bf(facc[i][3]) << 16);
        *(uint2*)&ctx_h[(size_t)(q0 + ty * 4 + i) * D_MODEL + tx * 4] = w;
    }
}

// ---------------------------------------------------------------------------
extern "C" void kernel_launch(void* const* d_in, const int* in_sizes, int n_in,
                              void* d_out, int out_size, void* d_ws, size_t ws_size,
                              hipStream_t stream)
{
    const float* q  = (const float*)d_in[0];
    const float* k  = (const float*)d_in[1];
    const float* v  = (const float*)d_in[2];
    const float* wq = (const float*)d_in[4];
    const float* bq = (const float*)d_in[5];
    const float* wk = (const float*)d_in[6];
    const float* bk = (const float*)d_in[7];
    const float* wv = (const float*)d_in[8];
    const float* bv = (const float*)d_in[9];
    const float* wo = (const float*)d_in[10];
    const float* bo = (const float*)d_in[11];

    float* out  = (float*)d_out;
    float* attn = out + (size_t)BATCH * SEQ * D_MODEL;

    const size_t NE = (size_t)MTOT * D_MODEL;     // 4194304
    const size_t WE = (size_t)D_MODEL * D_MODEL;  // 1048576
    unsigned short* ws  = (unsigned short*)d_ws;
    unsigned short* qb  = ws;
    unsigned short* kb  = qb + NE;
    unsigned short* vb  = kb + NE;
    unsigned short* wT  = vb + NE;                // 4 slabs: wq,wk,wv,wo transposed
    unsigned short* Qp  = wT + 4 * WE;            // (B,H,S,64) bf16
    unsigned short* Kp  = Qp + NE;
    unsigned short* Vp  = Kp + NE;
    unsigned short* ctxb = Vp + NE;               // (B,S,D) bf16

    const int n4 = (int)(NE / 4);
    cast_f32_bf16<<<(n4 + 255) / 256, 256, 0, stream>>>(q, qb, n4);
    cast_f32_bf16<<<(n4 + 255) / 256, 256, 0, stream>>>(k, kb, n4);
    cast_f32_bf16<<<(n4 + 255) / 256, 256, 0, stream>>>(v, vb, n4);
    transpose_cast_w<<<dim3(32, 32, 4), 256, 0, stream>>>(wq, wk, wv, wo, wT);

    gemm_mfma<<<dim3(32, 8, 3), 256, 0, stream>>>(qb, kb, vb, wT, bq, bk, bv,
                                                  Qp, Kp, Vp, nullptr, 0);

    dim3 ga(SEQ / 64, BATCH * NH);
    attn_fused<<<ga, 256, 0, stream>>>(Qp, Kp, Vp, attn, ctxb);

    gemm_mfma<<<dim3(32, 8, 1), 256, 0, stream>>>(ctxb, nullptr, nullptr, wT + 3 * WE,
                                                  bo, nullptr, nullptr,
                                                  nullptr, nullptr, nullptr, out, 1);
}